// Round 2
// baseline (412.623 us; speedup 1.0000x reference)
//
#include <hip/hip_runtime.h>

// FAC dynamic filter + leaky ReLU, fp32 in/out (per reference dtypes).
// feat:    [N=8, C=64, H=128, W=128] f32
// filters: [N, C*9, H, W] f32, filter channel = c*9 + (kh*3+kw)
// out:     [N, C, H, W] f32; out = leakyrelu_0.2(sum_t feat[h+kh-1, w+kw-1] * filt[c*9+t, h, w])
// Memory-bound: ~370 MB total, filters read dominates (302 MB, read exactly once,
// coalesced). Roofline floor ~59 us at 6.3 TB/s achievable.

#define N_ 8
#define C_ 64
#define H_ 128
#define W_ 128

typedef __attribute__((ext_vector_type(4))) float float4v; // 16 B = 4 f32

__global__ __launch_bounds__(256) void fac_kernel(
    const float* __restrict__ feat,
    const float* __restrict__ filt,
    float* __restrict__ out)
{
    // idx -> (n, c, h, w4); 32 groups of 4 along w
    int idx = blockIdx.x * 256 + threadIdx.x;
    int w0   = (idx & 31) << 2;      // w4 * 4
    int rest = idx >> 5;
    int h    = rest & (H_ - 1);
    rest   >>= 7;
    int c    = rest & (C_ - 1);
    int n    = rest >> 6;

    const float* fbase = feat + ((n * C_ + c) * H_) * W_;
    const float* wbase = filt + (((n * C_ + c) * 9) * H_ + h) * W_ + w0;

    float acc[4] = {0.f, 0.f, 0.f, 0.f};

    #pragma unroll
    for (int kh = 0; kh < 3; ++kh) {
        const int hh = h + kh - 1;
        float r[6];                  // feat row segment [w0-1 .. w0+4]
        if (hh >= 0 && hh < H_) {
            const float* row = fbase + hh * W_;
            const float4v v = *reinterpret_cast<const float4v*>(row + w0);
            r[1] = v[0]; r[2] = v[1]; r[3] = v[2]; r[4] = v[3];
            r[0] = (w0 > 0)      ? row[w0 - 1] : 0.f;
            r[5] = (w0 + 4 < W_) ? row[w0 + 4] : 0.f;
        } else {
            #pragma unroll
            for (int i = 0; i < 6; ++i) r[i] = 0.f;
        }

        #pragma unroll
        for (int kw = 0; kw < 3; ++kw) {
            const float4v wv =
                *reinterpret_cast<const float4v*>(wbase + (kh * 3 + kw) * (H_ * W_));
            #pragma unroll
            for (int j = 0; j < 4; ++j)
                acc[j] += r[j + kw] * wv[j];
        }
    }

    float4v o;
    #pragma unroll
    for (int j = 0; j < 4; ++j)
        o[j] = (acc[j] >= 0.f) ? acc[j] : 0.2f * acc[j];
    *reinterpret_cast<float4v*>(out + ((n * C_ + c) * H_ + h) * W_ + w0) = o;
}

extern "C" void kernel_launch(void* const* d_in, const int* in_sizes, int n_in,
                              void* d_out, int out_size, void* d_ws, size_t ws_size,
                              hipStream_t stream) {
    const float* feat = (const float*)d_in[0];
    const float* filt = (const float*)d_in[1];
    float* out = (float*)d_out;
    const int total_threads = N_ * C_ * H_ * (W_ / 4);   // 2,097,152
    fac_kernel<<<total_threads / 256, 256, 0, stream>>>(feat, filt, out);
}